// Round 3
// baseline (245.861 us; speedup 1.0000x reference)
//
#include <hip/hip_runtime.h>
#include <math.h>

// PersistenceLoss: BCE(y_true, y_pred) + 0.005 * topo
// topo: per 64x64 patch sort both tensors' values, mean squared diff of
// aligned order statistics. B=64, H=W=512 -> 4096 patches of 4096 elems.
//
// All-ascending (reversal-form) bitonic sort, 256 threads x 16 elems/thread:
//   merge_K = reversal stage (partner e ^ (K-1)) + plain xor stages, all CEs
//   ascending -> in-register stages are pure compile-time min/max.
// Cross-lane exchange primitives:
//   xor 1,2,3,7,8,15 : DPP (quad_perm / half_mirror / row_ror:8 / row_mirror)
//   xor 16,32        : v_permlane16/32_swap_b32 (VALU)
//   xor 4,31,63      : ds_swizzle / shfl (DS pipe)
//   t^64,127,255     : LDS, column-major buf[r*256+t] (conflict-free)

#define THREADS 256
#define EPT 16
#define PATCH_N 4096
#define NBLOCKS 4096

__device__ __forceinline__ void cea(float& lo, float& hi) {
    float mn = fminf(lo, hi);
    hi = fmaxf(lo, hi);
    lo = mn;
}

// partner value from lane ^ M (single-output paths)
template<int M>
__device__ __forceinline__ float lxor(float x) {
    if constexpr (M == 1 || M == 2 || M == 3 || M == 7 || M == 8 || M == 15) {
        constexpr int ctrl = (M == 1) ? 0xB1      // quad_perm [1,0,3,2]
                           : (M == 2) ? 0x4E      // quad_perm [2,3,0,1]
                           : (M == 3) ? 0x1B      // quad_perm [3,2,1,0]
                           : (M == 7) ? 0x141     // row_half_mirror
                           : (M == 8) ? 0x128     // row_ror:8
                           : 0x140;               // row_mirror (xor15)
        int xi = __float_as_int(x);
        return __int_as_float(__builtin_amdgcn_update_dpp(xi, xi, ctrl, 0xF, 0xF, true));
    } else if constexpr (M == 4) {
        return __int_as_float(__builtin_amdgcn_ds_swizzle(__float_as_int(x), 0x101F));
    } else if constexpr (M == 31) {
        return __int_as_float(__builtin_amdgcn_ds_swizzle(__float_as_int(x), 0x7C1F));
    } else {
        return __shfl_xor(x, M, 64);
    }
}

// permlane-swap CE: km ? max(x, A') : min(x, B') where {A',B'} = swap(x, x)
template<bool IS32>
__device__ __forceinline__ float plswap_ce(float x, bool km) {
    float A = x, B;
    if constexpr (IS32)
        asm("v_mov_b32 %1, %0\n\tv_permlane32_swap_b32 %0, %1" : "+v"(A), "=&v"(B));
    else
        asm("v_mov_b32 %1, %0\n\tv_permlane16_swap_b32 %0, %1" : "+v"(A), "=&v"(B));
    return km ? fmaxf(x, A) : fminf(x, B);
}

// plain xor stage, element stride j = 16*M, keepmax iff (t & M)
template<int M>
__device__ __forceinline__ void stage_lane2(float A[EPT], float B[EPT], int t) {
    const bool km = (t & M) != 0;
    #pragma unroll
    for (int r = 0; r < EPT; ++r) {
        if constexpr (M == 16) {
            A[r] = plswap_ce<false>(A[r], km);
            B[r] = plswap_ce<false>(B[r], km);
        } else if constexpr (M == 32) {
            A[r] = plswap_ce<true>(A[r], km);
            B[r] = plswap_ce<true>(B[r], km);
        } else {
            float oa = lxor<M>(A[r]);
            float ob = lxor<M>(B[r]);
            A[r] = km ? fmaxf(A[r], oa) : fminf(A[r], oa);
            B[r] = km ? fmaxf(B[r], ob) : fminf(B[r], ob);
        }
    }
}

// reversal stage of merge_K: partner (t ^ M, 15-r), keepmax iff (t & KB)
// M = (K-1)>>4, KB = K/32.  M in {1,3,7,15,31,63}.
template<int M, int KB>
__device__ __forceinline__ void stage_rev2(float A[EPT], float B[EPT], int t) {
    const bool km = (t & KB) != 0;
    #pragma unroll
    for (int r = 0; r < EPT / 2; ++r) {
        const int s = EPT - 1 - r;
        float xa = A[r], ya = A[s], xb = B[r], yb = B[s];
        float oxa = lxor<M>(ya), oya = lxor<M>(xa);
        float oxb = lxor<M>(yb), oyb = lxor<M>(xb);
        A[r] = km ? fmaxf(xa, oxa) : fminf(xa, oxa);
        A[s] = km ? fmaxf(ya, oya) : fminf(ya, oya);
        B[r] = km ? fmaxf(xb, oxb) : fminf(xb, oxb);
        B[s] = km ? fmaxf(yb, oyb) : fminf(yb, oyb);
    }
}

// cross-wave stage via LDS: partner thread t ^ TM, optional register reversal.
// Column-major buf[r*256 + t]: stride-1 across lanes both ways.
template<int TM, int KB, bool REV>
__device__ __forceinline__ void stage_lds2(float A[EPT], float B[EPT],
                                           float* bufA, float* bufB, int t) {
    #pragma unroll
    for (int r = 0; r < EPT; ++r) {
        bufA[r * THREADS + t] = A[r];
        bufB[r * THREADS + t] = B[r];
    }
    __syncthreads();
    const bool km = (t & KB) != 0;
    const int pt = t ^ TM;
    #pragma unroll
    for (int r = 0; r < EPT; ++r) {
        const int rr = REV ? (EPT - 1 - r) : r;
        float oa = bufA[rr * THREADS + pt];
        float ob = bufB[rr * THREADS + pt];
        A[r] = km ? fmaxf(A[r], oa) : fminf(A[r], oa);
        B[r] = km ? fmaxf(B[r], ob) : fminf(B[r], ob);
    }
    __syncthreads();
}

// in-register all-ascending tail: j = 8,4,2,1
__device__ __forceinline__ void tail2(float A[EPT], float B[EPT]) {
    #pragma unroll
    for (int j = 8; j >= 1; j >>= 1) {
        #pragma unroll
        for (int i = 0; i < EPT; ++i)
            if ((i & j) == 0) { cea(A[i], A[i | j]); cea(B[i], B[i | j]); }
    }
}

// full ascending sort of 16 in-register elements (reversal form, no directions)
__device__ __forceinline__ void sort16a(float v[EPT]) {
    #pragma unroll
    for (int i = 0; i < EPT; i += 2) cea(v[i], v[i + 1]);
    #pragma unroll
    for (int g = 0; g < EPT; g += 4) { cea(v[g], v[g + 3]); cea(v[g + 1], v[g + 2]); }
    #pragma unroll
    for (int g = 0; g < EPT; g += 4) { cea(v[g], v[g + 1]); cea(v[g + 2], v[g + 3]); }
    #pragma unroll
    for (int g = 0; g < EPT; g += 8) {
        cea(v[g], v[g + 7]); cea(v[g + 1], v[g + 6]);
        cea(v[g + 2], v[g + 5]); cea(v[g + 3], v[g + 4]);
    }
    #pragma unroll
    for (int g = 0; g < EPT; g += 8) {
        cea(v[g], v[g + 2]); cea(v[g + 1], v[g + 3]);
        cea(v[g + 4], v[g + 6]); cea(v[g + 5], v[g + 7]);
    }
    #pragma unroll
    for (int g = 0; g < EPT; g += 8) {
        cea(v[g], v[g + 1]); cea(v[g + 2], v[g + 3]);
        cea(v[g + 4], v[g + 5]); cea(v[g + 6], v[g + 7]);
    }
    #pragma unroll
    for (int i = 0; i < 8; ++i) cea(v[i], v[15 - i]);
    #pragma unroll
    for (int j = 4; j >= 1; j >>= 1) {
        #pragma unroll
        for (int i = 0; i < EPT; ++i)
            if ((i & j) == 0) cea(v[i], v[i | j]);
    }
}

__global__ __launch_bounds__(THREADS) void patch_sort_kernel(
    const float* __restrict__ y_true,
    const float* __restrict__ y_pred,
    float2* __restrict__ partials)
{
    __shared__ float bufA[PATCH_N];
    __shared__ float bufB[PATCH_N];

    const int bp = blockIdx.x;       // patch id 0..4095
    const int bb = bp >> 6;          // batch index
    const int p  = bp & 63;          // patch within image
    const int pr = p >> 3;
    const int pc = p & 7;
    const size_t base = (size_t)bb * (512 * 512)
                      + (size_t)pr * (64 * 512)
                      + (size_t)pc * 64;

    const int t = threadIdx.x;
    const size_t rowbase = base + (size_t)(t >> 2) * 512 + (size_t)(t & 3) * 16;

    float a[EPT], b[EPT];
    float bce = 0.0f;
    #pragma unroll
    for (int q = 0; q < 4; ++q) {
        float4 va = *reinterpret_cast<const float4*>(y_true + rowbase + q * 4);
        float4 vb = *reinterpret_cast<const float4*>(y_pred + rowbase + q * 4);
        a[q * 4 + 0] = va.x; a[q * 4 + 1] = va.y; a[q * 4 + 2] = va.z; a[q * 4 + 3] = va.w;
        b[q * 4 + 0] = vb.x; b[q * 4 + 1] = vb.y; b[q * 4 + 2] = vb.z; b[q * 4 + 3] = vb.w;
    }
    #pragma unroll
    for (int i = 0; i < EPT; ++i) {
        float yt = a[i];
        float pcl = fminf(fmaxf(b[i], 1e-7f), 1.0f - 1e-7f);
        bce -= yt * logf(pcl) + (1.0f - yt) * log1pf(-pcl);
    }

    // ---- all-ascending bitonic sort of both arrays ----
    sort16a(a); sort16a(b);
    // K = 32
    stage_rev2<1, 1>(a, b, t); tail2(a, b);
    // K = 64
    stage_rev2<3, 2>(a, b, t); stage_lane2<1>(a, b, t); tail2(a, b);
    // K = 128
    stage_rev2<7, 4>(a, b, t);
    stage_lane2<2>(a, b, t); stage_lane2<1>(a, b, t); tail2(a, b);
    // K = 256
    stage_rev2<15, 8>(a, b, t);
    stage_lane2<4>(a, b, t); stage_lane2<2>(a, b, t); stage_lane2<1>(a, b, t);
    tail2(a, b);
    // K = 512
    stage_rev2<31, 16>(a, b, t);
    stage_lane2<8>(a, b, t); stage_lane2<4>(a, b, t); stage_lane2<2>(a, b, t);
    stage_lane2<1>(a, b, t); tail2(a, b);
    // K = 1024
    stage_rev2<63, 32>(a, b, t);
    stage_lane2<16>(a, b, t); stage_lane2<8>(a, b, t); stage_lane2<4>(a, b, t);
    stage_lane2<2>(a, b, t); stage_lane2<1>(a, b, t); tail2(a, b);
    // K = 2048
    stage_lds2<127, 64, true>(a, b, bufA, bufB, t);
    stage_lane2<32>(a, b, t); stage_lane2<16>(a, b, t); stage_lane2<8>(a, b, t);
    stage_lane2<4>(a, b, t); stage_lane2<2>(a, b, t); stage_lane2<1>(a, b, t);
    tail2(a, b);
    // K = 4096
    stage_lds2<255, 128, true>(a, b, bufA, bufB, t);
    stage_lds2<64, 64, false>(a, b, bufA, bufB, t);
    stage_lane2<32>(a, b, t); stage_lane2<16>(a, b, t); stage_lane2<8>(a, b, t);
    stage_lane2<4>(a, b, t); stage_lane2<2>(a, b, t); stage_lane2<1>(a, b, t);
    tail2(a, b);

    // ---- squared diff of aligned order statistics ----
    float sq = 0.0f;
    #pragma unroll
    for (int i = 0; i < EPT; ++i) {
        float d = b[i] - a[i];
        sq += d * d;
    }

    // ---- block reduction: wave shuffle reduce, then 4 wave leaders ----
    #pragma unroll
    for (int off = 32; off >= 1; off >>= 1) {
        bce += __shfl_down(bce, off, 64);
        sq  += __shfl_down(sq, off, 64);
    }
    const int lane = t & 63;
    const int wid  = t >> 6;
    __syncthreads();
    if (lane == 0) { bufA[wid] = bce; bufB[wid] = sq; }
    __syncthreads();
    if (t == 0) {
        partials[bp] = make_float2(bufA[0] + bufA[1] + bufA[2] + bufA[3],
                                   bufB[0] + bufB[1] + bufB[2] + bufB[3]);
    }
}

__global__ __launch_bounds__(THREADS) void final_reduce_kernel(
    const float2* __restrict__ partials,
    float* __restrict__ out)
{
    __shared__ float rb[THREADS];
    __shared__ float rs[THREADS];
    const int tid = threadIdx.x;
    float bsum = 0.0f, ssum = 0.0f;
    for (int i = tid; i < NBLOCKS; i += THREADS) {
        float2 v = partials[i];
        bsum += v.x;
        ssum += v.y;
    }
    rb[tid] = bsum;
    rs[tid] = ssum;
    __syncthreads();
    for (int off = THREADS / 2; off > 0; off >>= 1) {
        if (tid < off) {
            rb[tid] += rb[tid + off];
            rs[tid] += rs[tid + off];
        }
        __syncthreads();
    }
    if (tid == 0) {
        // BCE mean and topo mean share denominator 64*512*512 = 16777216
        out[0] = (rb[0] + 0.005f * rs[0]) * (1.0f / 16777216.0f);
    }
}

extern "C" void kernel_launch(void* const* d_in, const int* in_sizes, int n_in,
                              void* d_out, int out_size, void* d_ws, size_t ws_size,
                              hipStream_t stream) {
    const float* y_true = (const float*)d_in[0];
    const float* y_pred = (const float*)d_in[1];
    float* out = (float*)d_out;
    float2* partials = (float2*)d_ws;   // 4096 * 8 B = 32 KB

    hipLaunchKernelGGL(patch_sort_kernel, dim3(NBLOCKS), dim3(THREADS), 0, stream,
                       y_true, y_pred, partials);
    hipLaunchKernelGGL(final_reduce_kernel, dim3(1), dim3(THREADS), 0, stream,
                       partials, out);
}